// Round 1
// baseline (4023.758 us; speedup 1.0000x reference)
//
#include <hip/hip_runtime.h>
#include <hip/hip_bf16.h>
#include <math.h>

#define BATCH 16
#define SEQ 4096
#define HDIM 64
#define NEG_INF (-3.0e38f)

// ---------------- QKV projection ----------------
// grid: B*T/64 blocks, 192 threads (3 waves: one per {Q,K,V} matrix).
// thread (mat, d): holds W[:,d] of its matrix in registers; x rows staged in
// LDS, read as wave-uniform float4 broadcasts (conflict-free).
__global__ __launch_bounds__(192)
void qkv_proj_kernel(const float* __restrict__ x,
                     const float* __restrict__ Wq,
                     const float* __restrict__ Wk,
                     const float* __restrict__ Wv,
                     float* __restrict__ q,
                     float* __restrict__ k,
                     float* __restrict__ v) {
    __shared__ float sx[64][HDIM];
    const int tid = threadIdx.x;
    const int mat = tid >> 6;        // 0,1,2
    const int d = tid & 63;
    const float* W = (mat == 0) ? Wq : (mat == 1) ? Wk : Wv;
    float* outp    = (mat == 0) ? q  : (mat == 1) ? k  : v;

    // W column d -> registers (coalesced across lanes: consecutive d)
    float w[HDIM];
    #pragma unroll
    for (int c = 0; c < HDIM; ++c) w[c] = W[c * HDIM + d];

    // stage 64 rows of x
    const size_t row0 = (size_t)blockIdx.x * 64;
    const float4* xs = (const float4*)(x + row0 * HDIM);
    float4* sx4 = (float4*)sx;
    for (int i = tid; i < 64 * HDIM / 4; i += 192) sx4[i] = xs[i];
    __syncthreads();

    for (int r = 0; r < 64; ++r) {
        const float4* xr = (const float4*)sx[r];
        float s = 0.f;
        #pragma unroll
        for (int c4 = 0; c4 < HDIM / 4; ++c4) {
            float4 xv = xr[c4];  // wave-uniform -> LDS broadcast
            s += xv.x * w[c4*4+0] + xv.y * w[c4*4+1]
               + xv.z * w[c4*4+2] + xv.w * w[c4*4+3];
        }
        outp[(row0 + r) * HDIM + d] = s;
    }
}

// ---------------- Flash attention (causal, fp32) ----------------
// grid: (T/128, B), 128 threads. Thread owns one q row: q(64) + acc(64) in
// VGPRs. K/V tiles of 64 rows staged in LDS; compute reads are wave-uniform
// broadcasts. Scores in groups of 16 (bounds register pressure), online
// softmax with per-group rescale.
#define BQ 128

__global__ __launch_bounds__(128)
void flash_kernel(const float* __restrict__ q,
                  const float* __restrict__ k,
                  const float* __restrict__ v,
                  float* __restrict__ out) {
    __shared__ float sk[64][HDIM];
    __shared__ float sv[64][HDIM];
    const int tid = threadIdx.x;
    const int b = blockIdx.y;
    const int qt = blockIdx.x;
    const int r = qt * BQ + tid;                    // this thread's q row
    const size_t bbase = (size_t)b * SEQ * HDIM;

    // q row, softmax scale folded in
    float4 qreg[HDIM/4];
    const float4* qp = (const float4*)(q + bbase + (size_t)r * HDIM);
    #pragma unroll
    for (int i = 0; i < HDIM/4; ++i) {
        float4 t4 = qp[i];
        t4.x *= 0.125f; t4.y *= 0.125f; t4.z *= 0.125f; t4.w *= 0.125f;
        qreg[i] = t4;
    }

    float m = NEG_INF, l = 0.f;
    float4 acc[HDIM/4];
    #pragma unroll
    for (int i = 0; i < HDIM/4; ++i) acc[i] = make_float4(0.f,0.f,0.f,0.f);

    const int ktiles = 2 * qt + 2;   // covers k rows 0 .. qt*128+127
    for (int t = 0; t < ktiles; ++t) {
        const int kbase = t * 64;
        __syncthreads();             // previous tile fully consumed
        {
            const float4* ks = (const float4*)(k + bbase + (size_t)kbase * HDIM);
            const float4* vs = (const float4*)(v + bbase + (size_t)kbase * HDIM);
            float4* sk4 = (float4*)sk;
            float4* sv4 = (float4*)sv;
            for (int i = tid; i < 64 * HDIM / 4; i += BQ) {
                sk4[i] = ks[i];
                sv4[i] = vs[i];
            }
        }
        __syncthreads();

        const bool full = (kbase + 63 <= r);  // no masking needed in this tile
        #pragma unroll 1
        for (int g = 0; g < 4; ++g) {
            float p[16];
            float gm = NEG_INF;
            #pragma unroll
            for (int jj = 0; jj < 16; ++jj) {
                const int j = g * 16 + jj;
                const float4* kr = (const float4*)sk[j];
                float s = 0.f;
                #pragma unroll
                for (int c4 = 0; c4 < HDIM/4; ++c4) {
                    float4 kk = kr[c4];   // broadcast
                    float4 qq = qreg[c4];
                    s += qq.x*kk.x + qq.y*kk.y + qq.z*kk.z + qq.w*kk.w;
                }
                if (!full && (kbase + j > r)) s = NEG_INF;
                p[jj] = s;
                gm = fmaxf(gm, s);
            }
            const float mnew = fmaxf(m, gm);
            const float alpha = __expf(m - mnew);  // m=-inf first time -> 0
            m = mnew;
            l *= alpha;
            #pragma unroll
            for (int i = 0; i < HDIM/4; ++i) {
                acc[i].x *= alpha; acc[i].y *= alpha;
                acc[i].z *= alpha; acc[i].w *= alpha;
            }
            #pragma unroll
            for (int jj = 0; jj < 16; ++jj) {
                const float pe = __expf(p[jj] - m);  // masked -> exp(-huge)=0
                l += pe;
                const float4* vr = (const float4*)sv[g*16+jj];
                #pragma unroll
                for (int c4 = 0; c4 < HDIM/4; ++c4) {
                    float4 vv = vr[c4];  // broadcast
                    acc[c4].x += pe * vv.x; acc[c4].y += pe * vv.y;
                    acc[c4].z += pe * vv.z; acc[c4].w += pe * vv.w;
                }
            }
        }
    }

    const float inv_l = 1.0f / l;
    float4* op = (float4*)(out + bbase + (size_t)r * HDIM);
    #pragma unroll
    for (int i = 0; i < HDIM/4; ++i) {
        float4 a = acc[i];
        a.x *= inv_l; a.y *= inv_l; a.z *= inv_l; a.w *= inv_l;
        op[i] = a;
    }
}

extern "C" void kernel_launch(void* const* d_in, const int* in_sizes, int n_in,
                              void* d_out, int out_size, void* d_ws, size_t ws_size,
                              hipStream_t stream) {
    const float* x  = (const float*)d_in[0];
    const float* Wq = (const float*)d_in[1];
    const float* Wk = (const float*)d_in[2];
    const float* Wv = (const float*)d_in[3];
    float* outp = (float*)d_out;

    const size_t elems = (size_t)BATCH * SEQ * HDIM;   // 4.19M
    float* q = (float*)d_ws;                            // 16 MB each
    float* k = q + elems;
    float* v = k + elems;                               // total 48 MB of d_ws

    qkv_proj_kernel<<<dim3(BATCH * SEQ / 64), 192, 0, stream>>>(x, Wq, Wk, Wv, q, k, v);
    flash_kernel<<<dim3(SEQ / BQ, BATCH), 128, 0, stream>>>(q, k, v, outp);
}

// Round 2
// 574.481 us; speedup vs baseline: 7.0042x; 7.0042x over previous
//
#include <hip/hip_runtime.h>
#include <hip/hip_bf16.h>
#include <math.h>

#define BATCH 16
#define SEQ 4096
#define HDIM 64

typedef __attribute__((ext_vector_type(8))) short bf16x8;   // 8 bf16 = 4 VGPR (guide §3)
typedef __attribute__((ext_vector_type(4))) float f32x4;
typedef __attribute__((ext_vector_type(8))) unsigned short us8;

#if __has_builtin(__builtin_amdgcn_exp2f)
#define EXP2F(x) __builtin_amdgcn_exp2f(x)
#else
#define EXP2F(x) exp2f(x)
#endif

// fold softmax scale (1/8) and log2(e) into Q so softmax runs in exp2 space
#define QSCALE 0.1803368801111601f  // 0.125 * log2(e)

// ---------------- QKV projection ----------------
// 192 threads = 3 waves (one per matrix). Thread (mat,d) holds W[:,d] in regs.
// Q written as bf16*QSCALE, K as bf16, V written TRANSPOSED as bf16 VT[b][d][t]
// (thread d owns v[:,d] across the 64 rows -> VT row d is thread-local).
__global__ __launch_bounds__(192)
void qkv_proj_kernel(const float* __restrict__ x,
                     const float* __restrict__ Wq,
                     const float* __restrict__ Wk,
                     const float* __restrict__ Wv,
                     __hip_bfloat16* __restrict__ qb,
                     __hip_bfloat16* __restrict__ kb,
                     __hip_bfloat16* __restrict__ vt) {
    __shared__ float sx[64][HDIM];
    const int tid = threadIdx.x;
    const int mat = tid >> 6;
    const int d = tid & 63;
    const float* W = (mat == 0) ? Wq : (mat == 1) ? Wk : Wv;

    float w[HDIM];
    #pragma unroll
    for (int c = 0; c < HDIM; ++c) w[c] = W[c * HDIM + d];

    const size_t row0 = (size_t)blockIdx.x * 64;
    const float4* xs = (const float4*)(x + row0 * HDIM);
    float4* sx4 = (float4*)sx;
    for (int i = tid; i < 64 * HDIM / 4; i += 192) sx4[i] = xs[i];
    __syncthreads();

    if (mat < 2) {
        __hip_bfloat16* outp = (mat == 0) ? qb : kb;
        const float sc = (mat == 0) ? QSCALE : 1.0f;
        for (int r = 0; r < 64; ++r) {
            const float4* xr = (const float4*)sx[r];
            float s = 0.f;
            #pragma unroll
            for (int c4 = 0; c4 < HDIM / 4; ++c4) {
                float4 xv = xr[c4];
                s += xv.x * w[c4*4+0] + xv.y * w[c4*4+1]
                   + xv.z * w[c4*4+2] + xv.w * w[c4*4+3];
            }
            outp[(row0 + r) * HDIM + d] = __float2bfloat16(s * sc);
        }
    } else {
        float vreg[64];
        for (int r = 0; r < 64; ++r) {
            const float4* xr = (const float4*)sx[r];
            float s = 0.f;
            #pragma unroll
            for (int c4 = 0; c4 < HDIM / 4; ++c4) {
                float4 xv = xr[c4];
                s += xv.x * w[c4*4+0] + xv.y * w[c4*4+1]
                   + xv.z * w[c4*4+2] + xv.w * w[c4*4+3];
            }
            vreg[r] = s;
        }
        const int batch = (int)(row0 >> 12);
        const int t0 = (int)(row0 & 4095);
        __hip_bfloat16* vrow = vt + ((size_t)batch * HDIM + d) * SEQ + t0;
        #pragma unroll
        for (int g = 0; g < 8; ++g) {
            us8 u;
            #pragma unroll
            for (int j = 0; j < 8; ++j) {
                __hip_bfloat16 h = __float2bfloat16(vreg[g*8 + j]);
                u[j] = *(unsigned short*)&h;
            }
            *(us8*)(vrow + g*8) = u;
        }
    }
}

// ---------------- MFMA flash attention ----------------
// Block 256 = 4 waves; wave owns 16 q-rows. Per 32-key step:
//   S[16x32] via 4 mfma_16x16x32_bf16 (A=Q frags, B=K rows as B^T frags),
//   causal mask, online softmax (exp2-space, shuffle row-max over quad group),
//   P -> per-wave LDS (no barrier: same-wave in-order DS) -> A-frag,
//   l via MFMA with all-ones B, 4 PV MFMAs with B = VT rows.
// C/D layout: col=lane&15, row=quad*4+reg (m89-verified).
// A layout:   m=lane&15,  k=quad*8+j     (m120-verified).
// B layout:   n=lane&15,  k=quad*8+j     (symmetric; m97 ref-checked GEMM).
__global__ __launch_bounds__(256)
void flash_mfma_kernel(const __hip_bfloat16* __restrict__ qb,
                       const __hip_bfloat16* __restrict__ kbuf,
                       const __hip_bfloat16* __restrict__ vt,
                       float* __restrict__ out) {
    __shared__ __attribute__((aligned(16))) __hip_bfloat16 pb[4][16][32];
    const int tid = threadIdx.x;
    const int wv = tid >> 6;
    const int lane = tid & 63;
    const int quad = lane >> 4;
    const int ml = lane & 15;
    const int b = blockIdx.y;
    const int qbase = blockIdx.x * 64 + wv * 16;
    const size_t bb = (size_t)b * SEQ * HDIM;

    const __hip_bfloat16* Q = qb + bb;
    const __hip_bfloat16* K = kbuf + bb;
    const __hip_bfloat16* VT = vt + bb;   // [b][64][SEQ]

    // Q A-frags (k = 0..31 and 32..63), row m = qbase+ml
    const bf16x8 a0 = *(const bf16x8*)(Q + (size_t)(qbase + ml) * HDIM + quad * 8);
    const bf16x8 a1 = *(const bf16x8*)(Q + (size_t)(qbase + ml) * HDIM + 32 + quad * 8);

    bf16x8 ones;
    #pragma unroll
    for (int j = 0; j < 8; ++j) ones[j] = (short)0x3F80;  // bf16 1.0

    f32x4 acc[4];
    #pragma unroll
    for (int nt = 0; nt < 4; ++nt) acc[nt] = (f32x4){0.f, 0.f, 0.f, 0.f};
    f32x4 lacc = (f32x4){0.f, 0.f, 0.f, 0.f};
    float mrow[4] = {-1e30f, -1e30f, -1e30f, -1e30f};

    const int klen = qbase + 16;   // keys 0..qbase+15 needed
    for (int kb0 = 0; kb0 < klen; kb0 += 32) {
        // K B^T frags: key n = kb0(+16)+ml, dims quad*8..+7 (+32)
        const bf16x8 b0l = *(const bf16x8*)(K + (size_t)(kb0 + ml) * HDIM + quad * 8);
        const bf16x8 b0h = *(const bf16x8*)(K + (size_t)(kb0 + ml) * HDIM + 32 + quad * 8);
        const bf16x8 b1l = *(const bf16x8*)(K + (size_t)(kb0 + 16 + ml) * HDIM + quad * 8);
        const bf16x8 b1h = *(const bf16x8*)(K + (size_t)(kb0 + 16 + ml) * HDIM + 32 + quad * 8);

        f32x4 s0 = __builtin_amdgcn_mfma_f32_16x16x32_bf16(a0, b0l, (f32x4){0.f,0.f,0.f,0.f}, 0, 0, 0);
        s0 = __builtin_amdgcn_mfma_f32_16x16x32_bf16(a1, b0h, s0, 0, 0, 0);
        f32x4 s1 = __builtin_amdgcn_mfma_f32_16x16x32_bf16(a0, b1l, (f32x4){0.f,0.f,0.f,0.f}, 0, 0, 0);
        s1 = __builtin_amdgcn_mfma_f32_16x16x32_bf16(a1, b1h, s1, 0, 0, 0);

        if (kb0 + 32 > qbase) {  // boundary: causal mask (key > row -> -inf)
            #pragma unroll
            for (int r = 0; r < 4; ++r) {
                const int row = qbase + quad * 4 + r;
                if (kb0 + ml > row)      s0[r] = -1e30f;
                if (kb0 + 16 + ml > row) s1[r] = -1e30f;
            }
        }

        // online softmax (exp2 space; scale folded into Q)
        float t[4], al[4], p0[4], p1[4];
        #pragma unroll
        for (int r = 0; r < 4; ++r) t[r] = fmaxf(s0[r], s1[r]);
        #pragma unroll
        for (int off = 1; off < 16; off <<= 1) {
            #pragma unroll
            for (int r = 0; r < 4; ++r) t[r] = fmaxf(t[r], __shfl_xor(t[r], off));
        }
        #pragma unroll
        for (int r = 0; r < 4; ++r) {
            const float mn = fmaxf(mrow[r], t[r]);
            al[r] = EXP2F(mrow[r] - mn);
            mrow[r] = mn;
            p0[r] = EXP2F(s0[r] - mn);
            p1[r] = EXP2F(s1[r] - mn);
        }
        #pragma unroll
        for (int r = 0; r < 4; ++r) {
            lacc[r] *= al[r];
            acc[0][r] *= al[r]; acc[1][r] *= al[r];
            acc[2][r] *= al[r]; acc[3][r] *= al[r];
        }

        // P -> LDS (C-layout scatter), then read back as A-frag
        #pragma unroll
        for (int r = 0; r < 4; ++r) {
            pb[wv][quad * 4 + r][ml]      = __float2bfloat16(p0[r]);
            pb[wv][quad * 4 + r][ml + 16] = __float2bfloat16(p1[r]);
        }
        __asm__ volatile("s_waitcnt lgkmcnt(0)" ::: "memory");  // same-wave DS ordering belt+braces
        const bf16x8 ap = *(const bf16x8*)&pb[wv][ml][quad * 8];

        // l row-sum via MFMA with all-ones B (replicates row sum across cols)
        lacc = __builtin_amdgcn_mfma_f32_16x16x32_bf16(ap, ones, lacc, 0, 0, 0);

        // PV: B = VT rows (dim nt*16+ml, keys kb0+quad*8..+7)
        #pragma unroll
        for (int nt = 0; nt < 4; ++nt) {
            const bf16x8 bv = *(const bf16x8*)(VT + (size_t)(nt * 16 + ml) * SEQ + kb0 + quad * 8);
            acc[nt] = __builtin_amdgcn_mfma_f32_16x16x32_bf16(ap, bv, acc[nt], 0, 0, 0);
        }
    }

    // epilogue: out[row][nt*16+ml] = acc/l  (C-layout: row=quad*4+r, col=ml)
    #pragma unroll
    for (int r = 0; r < 4; ++r) {
        const float inv = 1.0f / lacc[r];
        const int row = qbase + quad * 4 + r;
        float* orow = out + bb + (size_t)row * HDIM + ml;
        orow[0]  = acc[0][r] * inv;
        orow[16] = acc[1][r] * inv;
        orow[32] = acc[2][r] * inv;
        orow[48] = acc[3][r] * inv;
    }
}

extern "C" void kernel_launch(void* const* d_in, const int* in_sizes, int n_in,
                              void* d_out, int out_size, void* d_ws, size_t ws_size,
                              hipStream_t stream) {
    const float* x  = (const float*)d_in[0];
    const float* Wq = (const float*)d_in[1];
    const float* Wk = (const float*)d_in[2];
    const float* Wv = (const float*)d_in[3];
    float* outp = (float*)d_out;

    const size_t elems = (size_t)BATCH * SEQ * HDIM;     // 4.19M
    __hip_bfloat16* qb = (__hip_bfloat16*)d_ws;           // 8 MB
    __hip_bfloat16* kb = qb + elems;                      // 8 MB
    __hip_bfloat16* vt = kb + elems;                      // 8 MB (transposed [b][d][t])

    qkv_proj_kernel<<<dim3(BATCH * SEQ / 64), 192, 0, stream>>>(x, Wq, Wk, Wv, qb, kb, vt);
    flash_mfma_kernel<<<dim3(SEQ / 64, BATCH), 256, 0, stream>>>(qb, kb, vt, outp);
}

// Round 3
// 402.456 us; speedup vs baseline: 9.9980x; 1.4274x over previous
//
#include <hip/hip_runtime.h>
#include <hip/hip_bf16.h>
#include <math.h>

#define BATCH 16
#define SEQ 4096
#define HDIM 64

typedef __attribute__((ext_vector_type(8))) short bf16x8;   // 8 bf16 = 4 VGPR
typedef __attribute__((ext_vector_type(4))) float f32x4;
typedef __attribute__((ext_vector_type(8))) unsigned short us8;

// softmax scale (1/8) * log2(e) folded into Q -> softmax in exp2 space.
// No running max needed: |s| < ~25 worst-case => exp2 and fp32 sums can't overflow.
#define QSCALE 0.1803368801111601f

static __device__ __forceinline__ float exp2_fast(float x) {
#if __has_builtin(__builtin_amdgcn_exp2f)
    return __builtin_amdgcn_exp2f(x);
#else
    float r; asm("v_exp_f32 %0, %1" : "=v"(r) : "v"(x)); return r;
#endif
}

// ---------------- QKV projection ----------------
// 32 rows/block (2048 blocks -> 8/CU for latency hiding), 192 thr = 3 waves
// (one per matrix). Thread (mat,d) holds W[:,d] in regs. Q scaled by QSCALE,
// V written transposed VT[b][d][t] (thread-local rows, us8 stores).
__global__ __launch_bounds__(192)
void qkv_proj_kernel(const float* __restrict__ x,
                     const float* __restrict__ Wq,
                     const float* __restrict__ Wk,
                     const float* __restrict__ Wv,
                     __hip_bfloat16* __restrict__ qb,
                     __hip_bfloat16* __restrict__ kb,
                     __hip_bfloat16* __restrict__ vt) {
    __shared__ float sx[32][HDIM];
    const int tid = threadIdx.x;
    const int mat = tid >> 6;
    const int d = tid & 63;
    const float* W = (mat == 0) ? Wq : (mat == 1) ? Wk : Wv;

    float w[HDIM];
    #pragma unroll
    for (int c = 0; c < HDIM; ++c) w[c] = W[c * HDIM + d];

    const size_t row0 = (size_t)blockIdx.x * 32;
    const float4* xs = (const float4*)(x + row0 * HDIM);
    float4* sx4 = (float4*)sx;
    for (int i = tid; i < 32 * HDIM / 4; i += 192) sx4[i] = xs[i];
    __syncthreads();

    if (mat < 2) {
        __hip_bfloat16* outp = (mat == 0) ? qb : kb;
        const float sc = (mat == 0) ? QSCALE : 1.0f;
        #pragma unroll 4
        for (int r = 0; r < 32; ++r) {
            const float4* xr = (const float4*)sx[r];
            float s = 0.f;
            #pragma unroll
            for (int c4 = 0; c4 < HDIM / 4; ++c4) {
                float4 xv = xr[c4];
                s += xv.x * w[c4*4+0] + xv.y * w[c4*4+1]
                   + xv.z * w[c4*4+2] + xv.w * w[c4*4+3];
            }
            outp[(row0 + r) * HDIM + d] = __float2bfloat16(s * sc);
        }
    } else {
        float vreg[32];
        #pragma unroll 4
        for (int r = 0; r < 32; ++r) {
            const float4* xr = (const float4*)sx[r];
            float s = 0.f;
            #pragma unroll
            for (int c4 = 0; c4 < HDIM / 4; ++c4) {
                float4 xv = xr[c4];
                s += xv.x * w[c4*4+0] + xv.y * w[c4*4+1]
                   + xv.z * w[c4*4+2] + xv.w * w[c4*4+3];
            }
            vreg[r] = s;
        }
        const int batch = (int)(row0 >> 12);
        const int t0 = (int)(row0 & 4095);
        __hip_bfloat16* vrow = vt + ((size_t)batch * HDIM + d) * SEQ + t0;
        #pragma unroll
        for (int g = 0; g < 4; ++g) {
            us8 u;
            #pragma unroll
            for (int j = 0; j < 8; ++j) {
                __hip_bfloat16 h = __float2bfloat16(vreg[g*8 + j]);
                u[j] = *(unsigned short*)&h;
            }
            *(us8*)(vrow + g*8) = u;
        }
    }
}

// ---------------- MFMA flash attention, no-max softmax ----------------
// Block 256 = 4 waves; wave owns 16 q-rows; 64 keys/step.
// Per step: 16 independent global b128 loads (K,VT frags) issued at top;
// 8 S-MFMAs; p=exp2(s) (masked->0, no running max => no loop-carried
// softmax state); P->LDS (padded row 72) -> A-frags; 2 l-MFMAs (ones-B);
// 8 PV-MFMAs. Carried deps: acc/lacc MFMA accumulators only.
// Grid: flat 1024, id%8 = batch%8 -> XCD-local K/V (2 batches < 4MB L2);
// qt reversed so heaviest blocks launch first.
__global__ __launch_bounds__(256)
void flash_mfma_kernel(const __hip_bfloat16* __restrict__ qb,
                       const __hip_bfloat16* __restrict__ kbuf,
                       const __hip_bfloat16* __restrict__ vt,
                       float* __restrict__ out) {
    __shared__ __attribute__((aligned(16))) __hip_bfloat16 pb[4][16][72];  // +8 pad: bank-uniform A-frag reads
    const int tid = threadIdx.x;
    const int wv = tid >> 6;
    const int lane = tid & 63;
    const int quad = lane >> 4;
    const int ml = lane & 15;

    const int id = blockIdx.x;
    const int b = (((id >> 3) & 1) << 3) | (id & 7);  // batch; id%8 pins XCD
    const int qt = 63 - (id >> 4);                    // heavy blocks first
    const int qbase = qt * 64 + wv * 16;
    const size_t bb = (size_t)b * SEQ * HDIM;

    const __hip_bfloat16* Q = qb + bb;
    const __hip_bfloat16* K = kbuf + bb;
    const __hip_bfloat16* VT = vt + bb;   // [b][64][SEQ]

    // Q A-frags: row m = qbase+ml, k = quad*8.. (+32)
    const bf16x8 a0 = *(const bf16x8*)(Q + (size_t)(qbase + ml) * HDIM + quad * 8);
    const bf16x8 a1 = *(const bf16x8*)(Q + (size_t)(qbase + ml) * HDIM + 32 + quad * 8);

    bf16x8 ones;
    #pragma unroll
    for (int j = 0; j < 8; ++j) ones[j] = (short)0x3F80;  // bf16 1.0

    f32x4 acc[4];
    #pragma unroll
    for (int nt = 0; nt < 4; ++nt) acc[nt] = (f32x4){0.f, 0.f, 0.f, 0.f};
    f32x4 lacc = (f32x4){0.f, 0.f, 0.f, 0.f};

    const int klen = qbase + 16;
    for (int kb0 = 0; kb0 < klen; kb0 += 64) {
        // --- all 16 B-frag loads issued up front (independent, overlap) ---
        const __hip_bfloat16* kp = K + (size_t)(kb0 + ml) * HDIM + quad * 8;
        bf16x8 kl[4], kh[4];
        #pragma unroll
        for (int t = 0; t < 4; ++t) {
            kl[t] = *(const bf16x8*)(kp + t * 16 * HDIM);
            kh[t] = *(const bf16x8*)(kp + t * 16 * HDIM + 32);
        }
        const __hip_bfloat16* vp = VT + (size_t)ml * SEQ + kb0 + quad * 8;
        bf16x8 vl[4], vh[4];
        #pragma unroll
        for (int nt = 0; nt < 4; ++nt) {
            vl[nt] = *(const bf16x8*)(vp + (size_t)nt * 16 * SEQ);
            vh[nt] = *(const bf16x8*)(vp + (size_t)nt * 16 * SEQ + 32);
        }

        // --- S = Q K^T for 4 16-key tiles ---
        f32x4 s[4];
        #pragma unroll
        for (int t = 0; t < 4; ++t) {
            s[t] = __builtin_amdgcn_mfma_f32_16x16x32_bf16(a0, kl[t], (f32x4){0.f,0.f,0.f,0.f}, 0, 0, 0);
            s[t] = __builtin_amdgcn_mfma_f32_16x16x32_bf16(a1, kh[t], s[t], 0, 0, 0);
        }

        // --- p = exp2(s), causal zero at the boundary step, scatter to LDS ---
        const bool edge = (kb0 + 64 > qbase);
        #pragma unroll
        for (int t = 0; t < 4; ++t) {
            const int key = kb0 + t * 16 + ml;
            #pragma unroll
            for (int r = 0; r < 4; ++r) {
                float pv = exp2_fast(s[t][r]);
                if (edge && (key > qbase + quad * 4 + r)) pv = 0.f;
                pb[wv][quad * 4 + r][t * 16 + ml] = __float2bfloat16(pv);
            }
        }
        asm volatile("s_waitcnt lgkmcnt(0)" ::: "memory");
        const bf16x8 ap0 = *(const bf16x8*)&pb[wv][ml][quad * 8];
        const bf16x8 ap1 = *(const bf16x8*)&pb[wv][ml][32 + quad * 8];

        // --- l row-sums via ones-B MFMA; PV over 64 keys ---
        lacc = __builtin_amdgcn_mfma_f32_16x16x32_bf16(ap0, ones, lacc, 0, 0, 0);
        lacc = __builtin_amdgcn_mfma_f32_16x16x32_bf16(ap1, ones, lacc, 0, 0, 0);
        #pragma unroll
        for (int nt = 0; nt < 4; ++nt) {
            acc[nt] = __builtin_amdgcn_mfma_f32_16x16x32_bf16(ap0, vl[nt], acc[nt], 0, 0, 0);
            acc[nt] = __builtin_amdgcn_mfma_f32_16x16x32_bf16(ap1, vh[nt], acc[nt], 0, 0, 0);
        }
    }

    // epilogue: out[row][nt*16+ml] = acc/l (C-layout: row=quad*4+r, col=ml)
    #pragma unroll
    for (int r = 0; r < 4; ++r) {
        const float inv = 1.0f / lacc[r];
        const int row = qbase + quad * 4 + r;
        float* orow = out + bb + (size_t)row * HDIM + ml;
        orow[0]  = acc[0][r] * inv;
        orow[16] = acc[1][r] * inv;
        orow[32] = acc[2][r] * inv;
        orow[48] = acc[3][r] * inv;
    }
}

extern "C" void kernel_launch(void* const* d_in, const int* in_sizes, int n_in,
                              void* d_out, int out_size, void* d_ws, size_t ws_size,
                              hipStream_t stream) {
    const float* x  = (const float*)d_in[0];
    const float* Wq = (const float*)d_in[1];
    const float* Wk = (const float*)d_in[2];
    const float* Wv = (const float*)d_in[3];
    float* outp = (float*)d_out;

    const size_t elems = (size_t)BATCH * SEQ * HDIM;
    __hip_bfloat16* qb = (__hip_bfloat16*)d_ws;           // 8 MB
    __hip_bfloat16* kb = qb + elems;                      // 8 MB
    __hip_bfloat16* vt = kb + elems;                      // 8 MB, [b][d][t]

    qkv_proj_kernel<<<dim3(BATCH * SEQ / 32), 192, 0, stream>>>(x, Wq, Wk, Wv, qb, kb, vt);
    flash_mfma_kernel<<<dim3(BATCH * SEQ / 64), 256, 0, stream>>>(qb, kb, vt, outp);
}

// Round 4
// 188.369 us; speedup vs baseline: 21.3610x; 2.1365x over previous
//
#include <hip/hip_runtime.h>
#include <hip/hip_bf16.h>
#include <math.h>

#define BATCH 16
#define SEQ 4096
#define HDIM 64

typedef __attribute__((ext_vector_type(8))) short bf16x8;   // 8 bf16 = 4 VGPR
typedef __attribute__((ext_vector_type(4))) float f32x4;
typedef __attribute__((ext_vector_type(8))) unsigned short us8;

// softmax scale (1/8) * log2(e) folded into Q -> softmax in exp2 space.
// No running max: |s| < ~25 worst case => exp2/f32 sums can't overflow.
#define QSCALE 0.1803368801111601f

static __device__ __forceinline__ float exp2_fast(float x) {
#if __has_builtin(__builtin_amdgcn_exp2f)
    return __builtin_amdgcn_exp2f(x);
#else
    float r; asm("v_exp_f32 %0, %1" : "=v"(r) : "v"(x)); return r;
#endif
}

// async global->LDS, 16B/lane. LDS dest = wave-uniform base + lane*16 (m104).
static __device__ __forceinline__ void load_lds16(const void* g, void* l) {
    __builtin_amdgcn_global_load_lds(
        (const __attribute__((address_space(1))) unsigned int*)g,
        (__attribute__((address_space(3))) unsigned int*)l,
        16, 0, 0);
}

// ---------------- QKV projection ----------------
// 64 rows/block, 192 thr = 3 waves (one per matrix). Thread (mat,d) holds
// W[:,d] in regs. Q scaled by QSCALE. V transposed through LDS so the global
// VT[b][d][t] stores are 128B-contiguous rows (round-3's direct scatter
// stores cost ~90us of memory-pipe time).
__global__ __launch_bounds__(192)
void qkv_proj_kernel(const float* __restrict__ x,
                     const float* __restrict__ Wq,
                     const float* __restrict__ Wk,
                     const float* __restrict__ Wv,
                     __hip_bfloat16* __restrict__ qb,
                     __hip_bfloat16* __restrict__ kb,
                     __hip_bfloat16* __restrict__ vt) {
    __shared__ float sx[64][HDIM];
    __shared__ __attribute__((aligned(16))) __hip_bfloat16 svt[64][72];  // [d][t], pad->16B-aligned rows
    const int tid = threadIdx.x;
    const int mat = tid >> 6;
    const int d = tid & 63;
    const float* W = (mat == 0) ? Wq : (mat == 1) ? Wk : Wv;

    float w[HDIM];
    #pragma unroll
    for (int c = 0; c < HDIM; ++c) w[c] = W[c * HDIM + d];

    const size_t row0 = (size_t)blockIdx.x * 64;
    const float4* xs = (const float4*)(x + row0 * HDIM);
    float4* sx4 = (float4*)sx;
    for (int i = tid; i < 64 * HDIM / 4; i += 192) sx4[i] = xs[i];
    __syncthreads();

    if (mat < 2) {
        __hip_bfloat16* outp = (mat == 0) ? qb : kb;
        const float sc = (mat == 0) ? QSCALE : 1.0f;
        #pragma unroll 4
        for (int r = 0; r < 64; ++r) {
            const float4* xr = (const float4*)sx[r];
            float s = 0.f;
            #pragma unroll
            for (int c4 = 0; c4 < HDIM / 4; ++c4) {
                float4 xv = xr[c4];
                s += xv.x * w[c4*4+0] + xv.y * w[c4*4+1]
                   + xv.z * w[c4*4+2] + xv.w * w[c4*4+3];
            }
            outp[(row0 + r) * HDIM + d] = __float2bfloat16(s * sc);
        }
    } else {
        #pragma unroll 4
        for (int r = 0; r < 64; ++r) {
            const float4* xr = (const float4*)sx[r];
            float s = 0.f;
            #pragma unroll
            for (int c4 = 0; c4 < HDIM / 4; ++c4) {
                float4 xv = xr[c4];
                s += xv.x * w[c4*4+0] + xv.y * w[c4*4+1]
                   + xv.z * w[c4*4+2] + xv.w * w[c4*4+3];
            }
            svt[d][r] = __float2bfloat16(s);   // thread d owns VT row d
        }
    }
    __syncthreads();
    // cooperative coalesced VT store: 512 16B chunks, rows are 128B contiguous
    {
        const int batch = (int)(row0 >> 12);
        const int t0 = (int)(row0 & 4095);
        for (int c = tid; c < 512; c += 192) {
            const int row = c >> 3, g = c & 7;
            us8 u = *(const us8*)&svt[row][g * 8];
            *(us8*)(vt + ((size_t)batch * HDIM + row) * SEQ + t0 + g * 8) = u;
        }
    }
}

// ---------------- MFMA flash attention ----------------
// Block 256 = 4 waves (16 q-rows each); 64-key tiles SHARED by all 4 waves:
// K-tile (64x64) and VT-tile (64x64) staged to LDS via global_load_lds w=16
// (coalesced 1KB/instr; round-3 loaded the same frags 4x redundantly from
// global as 64B-segment scatters). Chunk-XOR swizzle (slot=row*8+(ch^row&7))
// since global_load_lds forbids padding; makes frag ds_read_b128 2-way (free).
// Softmax: no-max exp2 (scale folded in Q); P->padded LDS->A-frag; l via
// ones-B MFMA.
__global__ __launch_bounds__(256)
void flash_mfma_kernel(const __hip_bfloat16* __restrict__ qb,
                       const __hip_bfloat16* __restrict__ kbuf,
                       const __hip_bfloat16* __restrict__ vt,
                       float* __restrict__ out) {
    __shared__ __attribute__((aligned(16))) __hip_bfloat16 sk[64 * 64];
    __shared__ __attribute__((aligned(16))) __hip_bfloat16 sv[64 * 64];
    __shared__ __attribute__((aligned(16))) __hip_bfloat16 pb[4][16][72];
    const int tid = threadIdx.x;
    const int wv = tid >> 6;
    const int lane = tid & 63;
    const int quad = lane >> 4;
    const int ml = lane & 15;

    const int id = blockIdx.x;
    const int b = (((id >> 3) & 1) << 3) | (id & 7);  // id%8 pins XCD
    const int qt = 63 - (id >> 4);                    // heavy blocks first
    const int qbase = qt * 64 + wv * 16;
    const size_t bb = (size_t)b * SEQ * HDIM;

    const __hip_bfloat16* Q = qb + bb;
    const __hip_bfloat16* K = kbuf + bb;
    const __hip_bfloat16* VT = vt + bb;   // [b][64][SEQ]

    const bf16x8 a0 = *(const bf16x8*)(Q + (size_t)(qbase + ml) * HDIM + quad * 8);
    const bf16x8 a1 = *(const bf16x8*)(Q + (size_t)(qbase + ml) * HDIM + 32 + quad * 8);

    bf16x8 ones;
    #pragma unroll
    for (int j = 0; j < 8; ++j) ones[j] = (short)0x3F80;

    f32x4 acc[4];
    #pragma unroll
    for (int nt = 0; nt < 4; ++nt) acc[nt] = (f32x4){0.f, 0.f, 0.f, 0.f};
    f32x4 lacc = (f32x4){0.f, 0.f, 0.f, 0.f};

    // staging slots (2 rounds x 64 lanes per wave, 512 chunks per tile):
    // slot s holds global chunk (row=s>>3, ch=(s&7)^(row&7))  [XOR involution]
    const int s0 = wv * 128 + lane;
    const int s1 = s0 + 64;
    const int r0row = s0 >> 3, r0ch = (s0 & 7) ^ (r0row & 7);
    const int r1row = s1 >> 3, r1ch = (s1 & 7) ^ (r1row & 7);
    __hip_bfloat16* ldsb0k = sk + (size_t)(wv * 128) * 8;
    __hip_bfloat16* ldsb1k = sk + (size_t)(wv * 128 + 64) * 8;
    __hip_bfloat16* ldsb0v = sv + (size_t)(wv * 128) * 8;
    __hip_bfloat16* ldsb1v = sv + (size_t)(wv * 128 + 64) * 8;

    const int ntiles = qt + 1;
    for (int tile = 0; tile < ntiles; ++tile) {
        const int kb0 = tile * 64;
        __syncthreads();   // previous tile fully consumed by all waves
        load_lds16(K + (size_t)(kb0 + r0row) * HDIM + r0ch * 8, ldsb0k);
        load_lds16(K + (size_t)(kb0 + r1row) * HDIM + r1ch * 8, ldsb1k);
        load_lds16(VT + (size_t)r0row * SEQ + kb0 + r0ch * 8, ldsb0v);
        load_lds16(VT + (size_t)r1row * SEQ + kb0 + r1ch * 8, ldsb1v);
        asm volatile("s_waitcnt vmcnt(0)" ::: "memory");
        __syncthreads();   // tile staged

        // --- S = Q K^T: K frags from swizzled LDS (2-way reads = free) ---
        f32x4 s[4];
        #pragma unroll
        for (int t = 0; t < 4; ++t) {
            const int row = t * 16 + ml;
            const int rb = row << 3, rx = row & 7;
            const bf16x8 kl = *(const bf16x8*)(sk + (size_t)((rb | (quad ^ rx)) * 8));
            const bf16x8 kh = *(const bf16x8*)(sk + (size_t)((rb | ((quad + 4) ^ rx)) * 8));
            s[t] = __builtin_amdgcn_mfma_f32_16x16x32_bf16(a0, kl, (f32x4){0.f,0.f,0.f,0.f}, 0, 0, 0);
            s[t] = __builtin_amdgcn_mfma_f32_16x16x32_bf16(a1, kh, s[t], 0, 0, 0);
        }

        // --- p = exp2(s), causal zero on the diagonal tile, scatter to pb ---
        const bool edge = (tile == qt);
        #pragma unroll
        for (int t = 0; t < 4; ++t) {
            const int key = kb0 + t * 16 + ml;
            #pragma unroll
            for (int r = 0; r < 4; ++r) {
                float pv = exp2_fast(s[t][r]);
                if (edge && (key > qbase + quad * 4 + r)) pv = 0.f;
                pb[wv][quad * 4 + r][t * 16 + ml] = __float2bfloat16(pv);
            }
        }
        asm volatile("s_waitcnt lgkmcnt(0)" ::: "memory");
        const bf16x8 ap0 = *(const bf16x8*)&pb[wv][ml][quad * 8];
        const bf16x8 ap1 = *(const bf16x8*)&pb[wv][ml][32 + quad * 8];

        // --- l row-sums (ones-B MFMA) + PV with VT frags from LDS ---
        lacc = __builtin_amdgcn_mfma_f32_16x16x32_bf16(ap0, ones, lacc, 0, 0, 0);
        lacc = __builtin_amdgcn_mfma_f32_16x16x32_bf16(ap1, ones, lacc, 0, 0, 0);
        #pragma unroll
        for (int nt = 0; nt < 4; ++nt) {
            const int row = nt * 16 + ml;
            const int rb = row << 3, rx = row & 7;
            const bf16x8 vl = *(const bf16x8*)(sv + (size_t)((rb | (quad ^ rx)) * 8));
            const bf16x8 vh = *(const bf16x8*)(sv + (size_t)((rb | ((quad + 4) ^ rx)) * 8));
            acc[nt] = __builtin_amdgcn_mfma_f32_16x16x32_bf16(ap0, vl, acc[nt], 0, 0, 0);
            acc[nt] = __builtin_amdgcn_mfma_f32_16x16x32_bf16(ap1, vh, acc[nt], 0, 0, 0);
        }
    }

    // epilogue: out[row][nt*16+ml] = acc/l (C-layout: row=quad*4+r, col=ml)
    #pragma unroll
    for (int r = 0; r < 4; ++r) {
        const float inv = 1.0f / lacc[r];
        const int row = qbase + quad * 4 + r;
        float* orow = out + bb + (size_t)row * HDIM + ml;
        orow[0]  = acc[0][r] * inv;
        orow[16] = acc[1][r] * inv;
        orow[32] = acc[2][r] * inv;
        orow[48] = acc[3][r] * inv;
    }
}

extern "C" void kernel_launch(void* const* d_in, const int* in_sizes, int n_in,
                              void* d_out, int out_size, void* d_ws, size_t ws_size,
                              hipStream_t stream) {
    const float* x  = (const float*)d_in[0];
    const float* Wq = (const float*)d_in[1];
    const float* Wk = (const float*)d_in[2];
    const float* Wv = (const float*)d_in[3];
    float* outp = (float*)d_out;

    const size_t elems = (size_t)BATCH * SEQ * HDIM;
    __hip_bfloat16* qb = (__hip_bfloat16*)d_ws;           // 8 MB
    __hip_bfloat16* kb = qb + elems;                      // 8 MB
    __hip_bfloat16* vt = kb + elems;                      // 8 MB, [b][d][t]

    qkv_proj_kernel<<<dim3(BATCH * SEQ / 64), 192, 0, stream>>>(x, Wq, Wk, Wv, qb, kb, vt);
    flash_mfma_kernel<<<dim3(BATCH * SEQ / 64), 256, 0, stream>>>(qb, kb, vt, outp);
}

// Round 5
// 150.327 us; speedup vs baseline: 26.7668x; 1.2531x over previous
//
#include <hip/hip_runtime.h>
#include <hip/hip_bf16.h>
#include <math.h>

#define BATCH 16
#define SEQ 4096
#define HDIM 64

typedef __attribute__((ext_vector_type(8))) short bf16x8;   // 8 bf16 = 4 VGPR
typedef __attribute__((ext_vector_type(4))) float f32x4;
typedef __attribute__((ext_vector_type(8))) unsigned short us8;

// softmax scale (1/8) * log2(e) folded into Wq -> softmax in exp2 space.
// No running max: |s| < ~25 worst case => exp2/f32 sums can't overflow.
#define QSCALE 0.1803368801111601f

static __device__ __forceinline__ float exp2_fast(float x) {
#if __has_builtin(__builtin_amdgcn_exp2f)
    return __builtin_amdgcn_exp2f(x);
#else
    float r; asm("v_exp_f32 %0, %1" : "=v"(r) : "v"(x)); return r;
#endif
}

// async global->LDS, 16B/lane. LDS dest = wave-uniform base + lane*16 (m104).
static __device__ __forceinline__ void load_lds16(const void* g, void* l) {
    __builtin_amdgcn_global_load_lds(
        (const __attribute__((address_space(1))) unsigned int*)g,
        (__attribute__((address_space(3))) unsigned int*)l,
        16, 0, 0);
}

static __device__ __forceinline__ unsigned short bf16bits(float f) {
    __hip_bfloat16 h = __float2bfloat16(f);
    return *(unsigned short*)&h;
}

// ---------------- W prep ----------------
// Wt[mat][n][k] bf16, k-contiguous (B-frag-ready), chunk-XOR pre-swizzled:
// chunk c (k=c*8..c*8+7) of row n stored at slot c^(n&7). QSCALE folded into Wq.
// 24 blocks x 64 thr; thread -> one 16B chunk (8 strided W reads).
__global__ __launch_bounds__(64)
void wprep_kernel(const float* __restrict__ Wq, const float* __restrict__ Wk,
                  const float* __restrict__ Wv, __hip_bfloat16* __restrict__ wt) {
    const int mat = blockIdx.x >> 3;
    const int part = blockIdx.x & 7;
    const int t = threadIdx.x;
    const int n = part * 8 + (t >> 3);
    const int s = t & 7;
    const int c = s ^ (n & 7);
    const float* W = (mat == 0) ? Wq : (mat == 1) ? Wk : Wv;
    const float sc = (mat == 0) ? QSCALE : 1.0f;
    us8 u;
    #pragma unroll
    for (int j = 0; j < 8; ++j)
        u[j] = bf16bits(W[(c * 8 + j) * HDIM + n] * sc);
    *(us8*)(wt + (size_t)(mat * 64 + n) * 64 + s * 8) = u;
}

// ---------------- QKV projection as MFMA GEMM ----------------
// Round-2..4's proj did this work with wave-uniform LDS broadcast reads
// (16 B/instr to the whole wave) -- ~60us of pure LDS-issue per full pass,
// invariant to store-scheme changes. Here: 24 MFMAs/wave replace ~1024
// broadcast reads. 1024 blocks x 256 thr (4 waves, 16 rows each).
// x tile staged fp32 via global_load_lds (XOR-swizzled source addresses;
// each wave stages exactly its own 16 rows); Wt staged identity (pre-swizzled).
__global__ __launch_bounds__(256)
void qkv_mfma_kernel(const float* __restrict__ x,
                     const __hip_bfloat16* __restrict__ wt,
                     __hip_bfloat16* __restrict__ qb,
                     __hip_bfloat16* __restrict__ kb,
                     __hip_bfloat16* __restrict__ vt) {
    __shared__ __attribute__((aligned(16))) float sx[64 * 64];             // 16 KB
    __shared__ __attribute__((aligned(16))) __hip_bfloat16 swt[3 * 64 * 64]; // 24 KB
    __shared__ __attribute__((aligned(16))) __hip_bfloat16 svt[64][72];      // 9 KB
    const int tid = threadIdx.x;
    const int wv = tid >> 6;
    const int lane = tid & 63;
    const int quad = lane >> 4;
    const int ml = lane & 15;
    const size_t row0 = (size_t)blockIdx.x * 64;

    // stage x tile: slot (r, s) <- global chunk (r, c = s^(r&7)); wave wv's
    // slots [wv*256, wv*256+256) are exactly its own rows wv*16..+15
    #pragma unroll
    for (int i = 0; i < 4; ++i) {
        const int slotbase = (wv * 4 + i) * 64;
        const int slot = slotbase + lane;
        const int r = slot >> 4, s = slot & 15;
        const int c = s ^ (r & 7);
        load_lds16(x + (row0 + r) * HDIM + c * 4, (char*)sx + (size_t)slotbase * 16);
    }
    // stage Wt (identity: pre-swizzled in ws)
    #pragma unroll
    for (int i = 0; i < 6; ++i) {
        const int cb = (wv * 6 + i) * 64;
        load_lds16(wt + (size_t)(cb + lane) * 8, (char*)swt + (size_t)cb * 16);
    }
    asm volatile("s_waitcnt vmcnt(0)" ::: "memory");
    __syncthreads();

    // A-frags (rows wv*16+ml): chunks 2q,2q+1 (k<32) and 8+2q,9+2q (k>=32)
    const int rr = wv * 16 + ml;
    const int m7 = ml & 7;
    const float4* sx4 = (const float4*)sx;
    bf16x8 a0, a1;
    {
        float4 lo = sx4[rr * 16 + ((2 * quad) ^ m7)];
        float4 hi = sx4[rr * 16 + ((2 * quad + 1) ^ m7)];
        float t8[8] = {lo.x, lo.y, lo.z, lo.w, hi.x, hi.y, hi.z, hi.w};
        #pragma unroll
        for (int j = 0; j < 8; ++j) a0[j] = (short)bf16bits(t8[j]);
        lo = sx4[rr * 16 + ((8 + 2 * quad) ^ m7)];
        hi = sx4[rr * 16 + ((9 + 2 * quad) ^ m7)];
        float u8[8] = {lo.x, lo.y, lo.z, lo.w, hi.x, hi.y, hi.z, hi.w};
        #pragma unroll
        for (int j = 0; j < 8; ++j) a1[j] = (short)bf16bits(u8[j]);
    }

    f32x4 acc[3][4];
    #pragma unroll
    for (int mat = 0; mat < 3; ++mat)
        #pragma unroll
        for (int nt = 0; nt < 4; ++nt) acc[mat][nt] = (f32x4){0.f, 0.f, 0.f, 0.f};

    #pragma unroll
    for (int mat = 0; mat < 3; ++mat) {
        const __hip_bfloat16* wb = swt + mat * 64 * 64;
        #pragma unroll
        for (int nt = 0; nt < 4; ++nt) {
            const int n = nt * 16 + ml;
            const bf16x8 bl = *(const bf16x8*)(wb + (size_t)n * 64 + (size_t)((quad) ^ m7) * 8);
            const bf16x8 bh = *(const bf16x8*)(wb + (size_t)n * 64 + (size_t)((quad + 4) ^ m7) * 8);
            acc[mat][nt] = __builtin_amdgcn_mfma_f32_16x16x32_bf16(a0, bl, acc[mat][nt], 0, 0, 0);
            acc[mat][nt] = __builtin_amdgcn_mfma_f32_16x16x32_bf16(a1, bh, acc[mat][nt], 0, 0, 0);
        }
    }

    // Q/K: direct bf16 stores (C-layout; 32B segments, merged in L2 --
    // consumers read qb/kb from L2 anyway)
    #pragma unroll
    for (int mat = 0; mat < 2; ++mat) {
        __hip_bfloat16* outp = mat ? kb : qb;
        #pragma unroll
        for (int nt = 0; nt < 4; ++nt)
            #pragma unroll
            for (int r = 0; r < 4; ++r)
                outp[(row0 + wv * 16 + quad * 4 + r) * HDIM + nt * 16 + ml] =
                    __float2bfloat16(acc[mat][nt][r]);
    }
    // V -> svt transpose (per-wave-disjoint columns)
    #pragma unroll
    for (int nt = 0; nt < 4; ++nt)
        #pragma unroll
        for (int r = 0; r < 4; ++r)
            svt[nt * 16 + ml][wv * 16 + quad * 4 + r] = __float2bfloat16(acc[2][nt][r]);
    __syncthreads();

    // cooperative coalesced VT store: rows are 128B contiguous in global
    const int batch = (int)(row0 >> 12);
    const int t0 = (int)(row0 & 4095);
    #pragma unroll
    for (int c2 = 0; c2 < 2; ++c2) {
        const int cc = c2 * 256 + tid;
        const int row = cc >> 3, g = cc & 7;
        us8 u = *(const us8*)&svt[row][g * 8];
        *(us8*)(vt + ((size_t)batch * HDIM + row) * SEQ + t0 + g * 8) = u;
    }
}

// ---------------- MFMA flash attention (unchanged from round 4) ----------------
__global__ __launch_bounds__(256)
void flash_mfma_kernel(const __hip_bfloat16* __restrict__ qb,
                       const __hip_bfloat16* __restrict__ kbuf,
                       const __hip_bfloat16* __restrict__ vt,
                       float* __restrict__ out) {
    __shared__ __attribute__((aligned(16))) __hip_bfloat16 sk[64 * 64];
    __shared__ __attribute__((aligned(16))) __hip_bfloat16 sv[64 * 64];
    __shared__ __attribute__((aligned(16))) __hip_bfloat16 pb[4][16][72];
    const int tid = threadIdx.x;
    const int wv = tid >> 6;
    const int lane = tid & 63;
    const int quad = lane >> 4;
    const int ml = lane & 15;

    const int id = blockIdx.x;
    const int b = (((id >> 3) & 1) << 3) | (id & 7);  // id%8 pins XCD
    const int qt = 63 - (id >> 4);                    // heavy blocks first
    const int qbase = qt * 64 + wv * 16;
    const size_t bb = (size_t)b * SEQ * HDIM;

    const __hip_bfloat16* Q = qb + bb;
    const __hip_bfloat16* K = kbuf + bb;
    const __hip_bfloat16* VT = vt + bb;   // [b][64][SEQ]

    const bf16x8 a0 = *(const bf16x8*)(Q + (size_t)(qbase + ml) * HDIM + quad * 8);
    const bf16x8 a1 = *(const bf16x8*)(Q + (size_t)(qbase + ml) * HDIM + 32 + quad * 8);

    bf16x8 ones;
    #pragma unroll
    for (int j = 0; j < 8; ++j) ones[j] = (short)0x3F80;

    f32x4 acc[4];
    #pragma unroll
    for (int nt = 0; nt < 4; ++nt) acc[nt] = (f32x4){0.f, 0.f, 0.f, 0.f};
    f32x4 lacc = (f32x4){0.f, 0.f, 0.f, 0.f};

    const int s0 = wv * 128 + lane;
    const int s1 = s0 + 64;
    const int r0row = s0 >> 3, r0ch = (s0 & 7) ^ (r0row & 7);
    const int r1row = s1 >> 3, r1ch = (s1 & 7) ^ (r1row & 7);
    __hip_bfloat16* ldsb0k = sk + (size_t)(wv * 128) * 8;
    __hip_bfloat16* ldsb1k = sk + (size_t)(wv * 128 + 64) * 8;
    __hip_bfloat16* ldsb0v = sv + (size_t)(wv * 128) * 8;
    __hip_bfloat16* ldsb1v = sv + (size_t)(wv * 128 + 64) * 8;

    const int ntiles = qt + 1;
    for (int tile = 0; tile < ntiles; ++tile) {
        const int kb0 = tile * 64;
        __syncthreads();
        load_lds16(K + (size_t)(kb0 + r0row) * HDIM + r0ch * 8, ldsb0k);
        load_lds16(K + (size_t)(kb0 + r1row) * HDIM + r1ch * 8, ldsb1k);
        load_lds16(VT + (size_t)r0row * SEQ + kb0 + r0ch * 8, ldsb0v);
        load_lds16(VT + (size_t)r1row * SEQ + kb0 + r1ch * 8, ldsb1v);
        asm volatile("s_waitcnt vmcnt(0)" ::: "memory");
        __syncthreads();

        f32x4 s[4];
        #pragma unroll
        for (int t = 0; t < 4; ++t) {
            const int row = t * 16 + ml;
            const int rb = row << 3, rx = row & 7;
            const bf16x8 kl = *(const bf16x8*)(sk + (size_t)((rb | (quad ^ rx)) * 8));
            const bf16x8 kh = *(const bf16x8*)(sk + (size_t)((rb | ((quad + 4) ^ rx)) * 8));
            s[t] = __builtin_amdgcn_mfma_f32_16x16x32_bf16(a0, kl, (f32x4){0.f,0.f,0.f,0.f}, 0, 0, 0);
            s[t] = __builtin_amdgcn_mfma_f32_16x16x32_bf16(a1, kh, s[t], 0, 0, 0);
        }

        const bool edge = (tile == qt);
        #pragma unroll
        for (int t = 0; t < 4; ++t) {
            const int key = kb0 + t * 16 + ml;
            #pragma unroll
            for (int r = 0; r < 4; ++r) {
                float pv = exp2_fast(s[t][r]);
                if (edge && (key > qbase + quad * 4 + r)) pv = 0.f;
                pb[wv][quad * 4 + r][t * 16 + ml] = __float2bfloat16(pv);
            }
        }
        asm volatile("s_waitcnt lgkmcnt(0)" ::: "memory");
        const bf16x8 ap0 = *(const bf16x8*)&pb[wv][ml][quad * 8];
        const bf16x8 ap1 = *(const bf16x8*)&pb[wv][ml][32 + quad * 8];

        lacc = __builtin_amdgcn_mfma_f32_16x16x32_bf16(ap0, ones, lacc, 0, 0, 0);
        lacc = __builtin_amdgcn_mfma_f32_16x16x32_bf16(ap1, ones, lacc, 0, 0, 0);
        #pragma unroll
        for (int nt = 0; nt < 4; ++nt) {
            const int row = nt * 16 + ml;
            const int rb = row << 3, rx = row & 7;
            const bf16x8 vl = *(const bf16x8*)(sv + (size_t)((rb | (quad ^ rx)) * 8));
            const bf16x8 vh = *(const bf16x8*)(sv + (size_t)((rb | ((quad + 4) ^ rx)) * 8));
            acc[nt] = __builtin_amdgcn_mfma_f32_16x16x32_bf16(ap0, vl, acc[nt], 0, 0, 0);
            acc[nt] = __builtin_amdgcn_mfma_f32_16x16x32_bf16(ap1, vh, acc[nt], 0, 0, 0);
        }
    }

    #pragma unroll
    for (int r = 0; r < 4; ++r) {
        const float inv = 1.0f / lacc[r];
        const int row = qbase + quad * 4 + r;
        float* orow = out + bb + (size_t)row * HDIM + ml;
        orow[0]  = acc[0][r] * inv;
        orow[16] = acc[1][r] * inv;
        orow[32] = acc[2][r] * inv;
        orow[48] = acc[3][r] * inv;
    }
}

extern "C" void kernel_launch(void* const* d_in, const int* in_sizes, int n_in,
                              void* d_out, int out_size, void* d_ws, size_t ws_size,
                              hipStream_t stream) {
    const float* x  = (const float*)d_in[0];
    const float* Wq = (const float*)d_in[1];
    const float* Wk = (const float*)d_in[2];
    const float* Wv = (const float*)d_in[3];
    float* outp = (float*)d_out;

    const size_t elems = (size_t)BATCH * SEQ * HDIM;
    __hip_bfloat16* qb = (__hip_bfloat16*)d_ws;           // 8 MB
    __hip_bfloat16* kb = qb + elems;                      // 8 MB
    __hip_bfloat16* vt = kb + elems;                      // 8 MB, [b][d][t]
    __hip_bfloat16* wt = vt + elems;                      // 24 KB, pre-swizzled Wt

    wprep_kernel<<<dim3(24), 64, 0, stream>>>(Wq, Wk, Wv, wt);
    qkv_mfma_kernel<<<dim3(BATCH * SEQ / 64), 256, 0, stream>>>(x, wt, qb, kb, vt);
    flash_mfma_kernel<<<dim3(BATCH * SEQ / 64), 256, 0, stream>>>(qb, kb, vt, outp);
}